// Round 1
// baseline (434.108 us; speedup 1.0000x reference)
//
#include <hip/hip_runtime.h>
#include <cmath>

#define CIN   512
#define COUT  64
#define DBINS 41
#define NFEAT 105   // DBINS + COUT
#define HF    16
#define WF    44
#define NPIX  704   // HF*WF
#define NCAM  24    // B*N
#define NXG   128
#define NVOX  16384 // 128*128 (NX2 == 1)

// ---------------------------------------------------------------- utilities
__device__ __forceinline__ void inv3(const double a[9], double o[9]) {
    double c00 =  a[4]*a[8] - a[5]*a[7];
    double c01 = -(a[3]*a[8] - a[5]*a[6]);
    double c02 =  a[3]*a[7] - a[4]*a[6];
    double det = a[0]*c00 + a[1]*c01 + a[2]*c02;
    double id  = 1.0 / det;
    o[0] = c00 * id;
    o[1] = -(a[1]*a[8] - a[2]*a[7]) * id;
    o[2] =  (a[1]*a[5] - a[2]*a[4]) * id;
    o[3] = c01 * id;
    o[4] =  (a[0]*a[8] - a[2]*a[6]) * id;
    o[5] = -(a[0]*a[5] - a[2]*a[3]) * id;
    o[6] = c02 * id;
    o[7] = -(a[0]*a[7] - a[1]*a[6]) * id;
    o[8] =  (a[0]*a[4] - a[1]*a[3]) * id;
}

// --------------------------------------------------------- per-camera setup
// cams[i][0..8]  = inv(post_rots)
// cams[i][9..11] = post_trans
// cams[i][12..20]= rots @ inv(intrins)
// cams[i][21..23]= trans
__global__ void setup_cams_k(const float* __restrict__ rots,
                             const float* __restrict__ trans,
                             const float* __restrict__ intrins,
                             const float* __restrict__ post_rots,
                             const float* __restrict__ post_trans,
                             double* __restrict__ cams) {
    int i = blockIdx.x * blockDim.x + threadIdx.x;
    if (i >= NCAM) return;
    double R[9], K[9], PR[9], Kinv[9], PRinv[9];
    for (int k = 0; k < 9; ++k) {
        R[k]  = (double)rots[i*9 + k];
        K[k]  = (double)intrins[i*9 + k];
        PR[k] = (double)post_rots[i*9 + k];
    }
    inv3(K, Kinv);
    inv3(PR, PRinv);
    double* o = cams + (size_t)i * 24;
    for (int k = 0; k < 9; ++k) o[k] = PRinv[k];
    o[9]  = (double)post_trans[i*3 + 0];
    o[10] = (double)post_trans[i*3 + 1];
    o[11] = (double)post_trans[i*3 + 2];
    for (int r = 0; r < 3; ++r)
        for (int c = 0; c < 3; ++c)
            o[12 + r*3 + c] = R[r*3+0]*Kinv[0*3+c] + R[r*3+1]*Kinv[1*3+c] + R[r*3+2]*Kinv[2*3+c];
    o[21] = (double)trans[i*3 + 0];
    o[22] = (double)trans[i*3 + 1];
    o[23] = (double)trans[i*3 + 2];
}

// --------------------------------------------------------------- 1x1 conv GEMM
// x: [NCAM][CIN][NPIX], w: [NFEAT][CIN], feat: [2][NCAM][NPIX][NFEAT]
// K split in half across blockIdx parity; halves summed by the scatter kernel.
__global__ __launch_bounds__(256) void gemm_feat_k(const float* __restrict__ x,
                                                   const float* __restrict__ w,
                                                   const float* __restrict__ bias,
                                                   float* __restrict__ feat) {
    __shared__ float tbuf[64 * NFEAT];
    int bx   = blockIdx.x;      // 0..527
    int kh   = bx & 1;          // K half
    int tile = bx >> 1;         // 0..263
    int bn   = tile / 11;
    int p0   = (tile - bn * 11) * 64;
    int px   = threadIdx.x & 63;
    int og   = threadIdx.x >> 6;   // 0..3
    int obase = og * 27;           // og=3 covers 81..104 (24 outputs)

    float acc[27];
    #pragma unroll
    for (int i = 0; i < 27; ++i) acc[i] = 0.0f;

    const float* xp = x + ((size_t)bn * CIN + (size_t)kh * 256) * NPIX + p0 + px;
    const float* wp = w + (size_t)kh * 256;

    for (int c0 = 0; c0 < 256; c0 += 4) {
        float x0 = xp[(size_t)(c0 + 0) * NPIX];
        float x1 = xp[(size_t)(c0 + 1) * NPIX];
        float x2 = xp[(size_t)(c0 + 2) * NPIX];
        float x3 = xp[(size_t)(c0 + 3) * NPIX];
        #pragma unroll
        for (int i = 0; i < 27; ++i) {
            if (obase + i < NFEAT) {
                const float4 wv = *reinterpret_cast<const float4*>(wp + (size_t)(obase + i) * CIN + c0);
                acc[i] = fmaf(wv.x, x0, acc[i]);
                acc[i] = fmaf(wv.y, x1, acc[i]);
                acc[i] = fmaf(wv.z, x2, acc[i]);
                acc[i] = fmaf(wv.w, x3, acc[i]);
            }
        }
    }

    #pragma unroll
    for (int i = 0; i < 27; ++i) {
        int o = obase + i;
        if (o < NFEAT) tbuf[px * NFEAT + o] = acc[i] + (kh == 0 ? bias[o] : 0.0f);
    }
    __syncthreads();
    // contiguous coalesced store: feat[kh][bn][p0..p0+63][0..104]
    float* dst = feat + ((size_t)(kh * NCAM + bn) * NPIX + p0) * NFEAT;
    for (int idx = threadIdx.x; idx < 64 * NFEAT; idx += 256) dst[idx] = tbuf[idx];
}

// -------------------------------------------- fused softmax+geometry+scatter
// One wave per pixel. lane == output channel for the atomic phase.
__global__ __launch_bounds__(64) void scatter_k(const float* __restrict__ feat,
                                                const double* __restrict__ cams,
                                                float* __restrict__ bev) {
    int pix = blockIdx.x;            // 0..16895
    int bn  = pix / NPIX;
    int p   = pix - bn * NPIX;
    int h   = p / WF;
    int wpx = p - h * WF;
    int lane = threadIdx.x;

    __shared__ float f[NFEAT];
    __shared__ float dep[DBINS];
    __shared__ int   rnk[DBINS];

    const float* f0 = feat + ((size_t)bn * NPIX + p) * NFEAT;
    const float* f1 = feat + ((size_t)(NCAM + bn) * NPIX + p) * NFEAT;
    for (int o = lane; o < NFEAT; o += 64) f[o] = f0[o] + f1[o];
    __syncthreads();

    // softmax over f[0..40]
    float v = (lane < DBINS) ? f[lane] : -1e30f;
    float m = v;
    #pragma unroll
    for (int o = 32; o > 0; o >>= 1) m = fmaxf(m, __shfl_xor(m, o, 64));
    float e = (lane < DBINS) ? expf(v - m) : 0.0f;
    float s = e;
    #pragma unroll
    for (int o = 32; o > 0; o >>= 1) s += __shfl_xor(s, o, 64);

    if (lane < DBINS) {
        dep[lane] = e / s;
        // geometry for depth bin `lane`
        const double* cm = cams + (size_t)bn * 24;
        double dd = 4.0 + (double)lane;
        double ax = (double)wpx - cm[9];
        double ay = (double)h   - cm[10];
        double az = dd          - cm[11];
        double q0 = cm[0]*ax + cm[1]*ay + cm[2]*az;
        double q1 = cm[3]*ax + cm[4]*ay + cm[5]*az;
        double q2 = cm[6]*ax + cm[7]*ay + cm[8]*az;
        double r0 = q0 * q2, r1 = q1 * q2, r2 = q2;
        double sx = cm[12]*r0 + cm[13]*r1 + cm[14]*r2 + cm[21];
        double sy = cm[15]*r0 + cm[16]*r1 + cm[17]*r2 + cm[22];
        double sz = cm[18]*r0 + cm[19]*r1 + cm[20]*r2 + cm[23];
        // trunc-toward-zero matches .astype(int32)
        int cx = (int)((sx + 50.8) / 0.8);
        int cy = (int)((sy + 50.8) / 0.8);
        int cz = (int)(sz / 20.0);
        bool ok = (cx >= 0) && (cx < NXG) && (cy >= 0) && (cy < NXG) && (cz == 0);
        rnk[lane] = ok ? (cy * NXG + cx) : -1;
    }
    __syncthreads();

    float tr = f[DBINS + lane];           // this lane's channel value
    for (int d = 0; d < DBINS; ++d) {
        int r = rnk[d];
        if (r >= 0) {
            atomicAdd(&bev[(size_t)r * COUT + lane], dep[d] * tr);
        }
    }
}

// -------------------------------------------------------- [r][c] -> [c][r]
__global__ __launch_bounds__(256) void transpose_k(const float* __restrict__ bev,
                                                   float* __restrict__ out) {
    __shared__ float t[64][65];
    int r0 = blockIdx.x * 64;           // 256 blocks
    int c  = threadIdx.x & 63;
    int r4 = threadIdx.x >> 6;          // 0..3
    #pragma unroll
    for (int i = 0; i < 16; ++i) {
        int r = r4 + i * 4;
        t[r][c] = bev[(size_t)(r0 + r) * COUT + c];
    }
    __syncthreads();
    int rl  = threadIdx.x & 63;
    int cc0 = threadIdx.x >> 6;
    #pragma unroll
    for (int i = 0; i < 16; ++i) {
        int ch = cc0 + i * 4;
        out[(size_t)ch * NVOX + r0 + rl] = t[rl][ch];
    }
}

// --------------------------------------------------------------------- launch
extern "C" void kernel_launch(void* const* d_in, const int* in_sizes, int n_in,
                              void* d_out, int out_size, void* d_ws, size_t ws_size,
                              hipStream_t stream) {
    const float* img   = (const float*)d_in[0];
    const float* dw    = (const float*)d_in[1];
    const float* db    = (const float*)d_in[2];
    const float* rots  = (const float*)d_in[3];
    const float* trans = (const float*)d_in[4];
    const float* intr  = (const float*)d_in[5];
    const float* prot  = (const float*)d_in[6];
    const float* ptrn  = (const float*)d_in[7];
    float* out = (float*)d_out;

    char* ws = (char*)d_ws;
    double* cams = (double*)ws;                                   // 4608 B
    float*  feat = (float*)(ws + 8192);                           // 2*24*704*105*4 = 14,192,640 B
    float*  bev  = (float*)(ws + 8192 + (size_t)2 * NCAM * NPIX * NFEAT * 4); // 4 MB

    hipMemsetAsync(bev, 0, (size_t)NVOX * COUT * sizeof(float), stream);
    setup_cams_k<<<1, 64, 0, stream>>>(rots, trans, intr, prot, ptrn, cams);
    gemm_feat_k<<<528, 256, 0, stream>>>(img, dw, db, feat);
    scatter_k<<<NCAM * NPIX, 64, 0, stream>>>(feat, cams, bev);
    transpose_k<<<NVOX / 64, 256, 0, stream>>>(bev, out);
}

// Round 3
// 294.412 us; speedup vs baseline: 1.4745x; 1.4745x over previous
//
#include <hip/hip_runtime.h>
#include <cmath>

#define CIN   512
#define COUT  64
#define DBINS 41
#define NFEAT 105   // DBINS + COUT
#define HF    16
#define WF    44
#define NPIX  704   // HF*WF
#define NCAM  24    // B*N
#define NXG   128
#define NVOX  16384 // 128*128 (NX2 == 1)

// ---------------------------------------------------------------- utilities
__device__ __forceinline__ void inv3(const double a[9], double o[9]) {
    double c00 =  a[4]*a[8] - a[5]*a[7];
    double c01 = -(a[3]*a[8] - a[5]*a[6]);
    double c02 =  a[3]*a[7] - a[4]*a[6];
    double det = a[0]*c00 + a[1]*c01 + a[2]*c02;
    double id  = 1.0 / det;
    o[0] = c00 * id;
    o[1] = -(a[1]*a[8] - a[2]*a[7]) * id;
    o[2] =  (a[1]*a[5] - a[2]*a[4]) * id;
    o[3] = c01 * id;
    o[4] =  (a[0]*a[8] - a[2]*a[6]) * id;
    o[5] = -(a[0]*a[5] - a[2]*a[3]) * id;
    o[6] = c02 * id;
    o[7] = -(a[0]*a[7] - a[1]*a[6]) * id;
    o[8] =  (a[0]*a[4] - a[1]*a[3]) * id;
}

// --------------------------------------------------------- per-camera setup
__global__ void setup_cams_k(const float* __restrict__ rots,
                             const float* __restrict__ trans,
                             const float* __restrict__ intrins,
                             const float* __restrict__ post_rots,
                             const float* __restrict__ post_trans,
                             double* __restrict__ cams) {
    int i = blockIdx.x * blockDim.x + threadIdx.x;
    if (i >= NCAM) return;
    double R[9], K[9], PR[9], Kinv[9], PRinv[9];
    for (int k = 0; k < 9; ++k) {
        R[k]  = (double)rots[i*9 + k];
        K[k]  = (double)intrins[i*9 + k];
        PR[k] = (double)post_rots[i*9 + k];
    }
    inv3(K, Kinv);
    inv3(PR, PRinv);
    double* o = cams + (size_t)i * 24;
    for (int k = 0; k < 9; ++k) o[k] = PRinv[k];
    o[9]  = (double)post_trans[i*3 + 0];
    o[10] = (double)post_trans[i*3 + 1];
    o[11] = (double)post_trans[i*3 + 2];
    for (int r = 0; r < 3; ++r)
        for (int c = 0; c < 3; ++c)
            o[12 + r*3 + c] = R[r*3+0]*Kinv[0*3+c] + R[r*3+1]*Kinv[1*3+c] + R[r*3+2]*Kinv[2*3+c];
    o[21] = (double)trans[i*3 + 0];
    o[22] = (double)trans[i*3 + 1];
    o[23] = (double)trans[i*3 + 2];
}

// --------------------------------------------------------------- 1x1 conv GEMM
// x: [NCAM][CIN][NPIX], w: [NFEAT][CIN], feat: [2][NCAM][NPIX][NFEAT]
// Tile: M=64 px (lane), N=112 (8 waves x 14 outs), K=256 (kh half), BK=64.
// x staged k-blocked: xs[kq][px][j] = x[kbase+4*kq+j][p0+px]  (no swizzle needed)
// w staged row-major [112][64], read wave-uniform (LDS broadcast).
__global__ __launch_bounds__(512) void gemm_feat_k(const float* __restrict__ x,
                                                   const float* __restrict__ w,
                                                   const float* __restrict__ bias,
                                                   float* __restrict__ feat) {
    __shared__ float xs[16][64][4];   // 16 KB
    __shared__ float wsm[64 * 113];   // 28,928 B; as w-tile [112][64] then out-tile [64][113]

    int bx   = blockIdx.x;            // 0..527
    int kh   = bx & 1;
    int tile = bx >> 1;               // 0..263
    int bn   = tile / 11;
    int p0   = (tile - bn * 11) * 64;
    int lane = threadIdx.x & 63;      // px within tile
    int wid  = threadIdx.x >> 6;      // 0..7 -> out group of 14

    float acc[14];
    #pragma unroll
    for (int i = 0; i < 14; ++i) acc[i] = 0.0f;

    for (int kt = 0; kt < 4; ++kt) {
        int kbase = kh * 256 + kt * 64;
        // ---- stage x tile: 64 k x 64 px (1024 float4s, 2 per thread)
        #pragma unroll
        for (int pass = 0; pass < 2; ++pass) {
            int idx = threadIdx.x + pass * 512;   // 0..1023
            int px  = idx & 63;
            int kq  = idx >> 6;                   // 0..15
            const float* g = x + ((size_t)bn * CIN + kbase + (kq << 2)) * NPIX + p0 + px;
            xs[kq][px][0] = g[0 * NPIX];
            xs[kq][px][1] = g[1 * NPIX];
            xs[kq][px][2] = g[2 * NPIX];
            xs[kq][px][3] = g[3 * NPIX];
        }
        // ---- stage w tile: [112][64] row-major (rows 105..111 zero)
        #pragma unroll
        for (int pass = 0; pass < 4; ++pass) {
            int idx = threadIdx.x + pass * 512;   // 0..2047
            int o   = idx >> 4;                   // 0..127
            int ci  = (idx & 15) << 2;
            if (o < 112) {
                float4 wv = make_float4(0.f, 0.f, 0.f, 0.f);
                if (o < 105)
                    wv = *reinterpret_cast<const float4*>(w + (size_t)o * CIN + kbase + ci);
                *reinterpret_cast<float4*>(&wsm[o * 64 + ci]) = wv;
            }
        }
        __syncthreads();
        // ---- compute: per 4-k step, 1 lane-b128 (x) + 14 uniform-b128 (w) + 56 FMA
        #pragma unroll 4
        for (int kq = 0; kq < 16; ++kq) {
            float4 xv = *reinterpret_cast<const float4*>(&xs[kq][lane][0]);
            #pragma unroll
            for (int i = 0; i < 14; ++i) {
                float4 wv = *reinterpret_cast<const float4*>(&wsm[(wid * 14 + i) * 64 + (kq << 2)]);
                acc[i] = fmaf(xv.x, wv.x, acc[i]);
                acc[i] = fmaf(xv.y, wv.y, acc[i]);
                acc[i] = fmaf(xv.z, wv.z, acc[i]);
                acc[i] = fmaf(xv.w, wv.w, acc[i]);
            }
        }
        __syncthreads();
    }

    // ---- epilogue: out-tile [64 px][113] (odd stride -> conflict-free), coalesced store
    #pragma unroll
    for (int i = 0; i < 14; ++i) {
        int o = wid * 14 + i;
        if (o < NFEAT) {
            float b = (kh == 0) ? bias[o] : 0.0f;
            wsm[lane * 113 + o] = acc[i] + b;
        }
    }
    __syncthreads();
    float* dst = feat + ((size_t)(kh * NCAM + bn) * NPIX + p0) * NFEAT;
    for (int idx = threadIdx.x; idx < 64 * NFEAT; idx += 512) {
        int px = idx / NFEAT;
        int o  = idx - px * NFEAT;
        dst[idx] = wsm[px * 113 + o];
    }
}

// -------------------------------------------- fused softmax+geometry+scatter
// (round-1 verbatim: one 64-thread block per pixel; known-good)
__global__ __launch_bounds__(64) void scatter_k(const float* __restrict__ feat,
                                                const double* __restrict__ cams,
                                                float* __restrict__ bev) {
    int pix = blockIdx.x;            // 0..16895
    int bn  = pix / NPIX;
    int p   = pix - bn * NPIX;
    int h   = p / WF;
    int wpx = p - h * WF;
    int lane = threadIdx.x;

    __shared__ float f[NFEAT];
    __shared__ float dep[DBINS];
    __shared__ int   rnk[DBINS];

    const float* f0 = feat + ((size_t)bn * NPIX + p) * NFEAT;
    const float* f1 = feat + ((size_t)(NCAM + bn) * NPIX + p) * NFEAT;
    for (int o = lane; o < NFEAT; o += 64) f[o] = f0[o] + f1[o];
    __syncthreads();

    // softmax over f[0..40]
    float v = (lane < DBINS) ? f[lane] : -1e30f;
    float m = v;
    #pragma unroll
    for (int o = 32; o > 0; o >>= 1) m = fmaxf(m, __shfl_xor(m, o, 64));
    float e = (lane < DBINS) ? expf(v - m) : 0.0f;
    float s = e;
    #pragma unroll
    for (int o = 32; o > 0; o >>= 1) s += __shfl_xor(s, o, 64);

    if (lane < DBINS) {
        dep[lane] = e / s;
        const double* cm = cams + (size_t)bn * 24;
        double dd = 4.0 + (double)lane;
        double ax = (double)wpx - cm[9];
        double ay = (double)h   - cm[10];
        double az = dd          - cm[11];
        double q0 = cm[0]*ax + cm[1]*ay + cm[2]*az;
        double q1 = cm[3]*ax + cm[4]*ay + cm[5]*az;
        double q2 = cm[6]*ax + cm[7]*ay + cm[8]*az;
        double r0 = q0 * q2, r1 = q1 * q2, r2 = q2;
        double sx = cm[12]*r0 + cm[13]*r1 + cm[14]*r2 + cm[21];
        double sy = cm[15]*r0 + cm[16]*r1 + cm[17]*r2 + cm[22];
        double sz = cm[18]*r0 + cm[19]*r1 + cm[20]*r2 + cm[23];
        int cx = (int)((sx + 50.8) / 0.8);   // trunc == .astype(int32)
        int cy = (int)((sy + 50.8) / 0.8);
        int cz = (int)(sz / 20.0);
        bool ok = (cx >= 0) && (cx < NXG) && (cy >= 0) && (cy < NXG) && (cz == 0);
        rnk[lane] = ok ? (cy * NXG + cx) : -1;
    }
    __syncthreads();

    float tr = f[DBINS + lane];           // this lane's channel value
    for (int d = 0; d < DBINS; ++d) {
        int r = rnk[d];
        if (r >= 0) {
            atomicAdd(&bev[(size_t)r * COUT + lane], dep[d] * tr);
        }
    }
}

// -------------------------------------------------------- [r][c] -> [c][r]
__global__ __launch_bounds__(256) void transpose_k(const float* __restrict__ bev,
                                                   float* __restrict__ out) {
    __shared__ float t[64][65];
    int r0 = blockIdx.x * 64;
    int c  = threadIdx.x & 63;
    int r4 = threadIdx.x >> 6;
    #pragma unroll
    for (int i = 0; i < 16; ++i) {
        int r = r4 + i * 4;
        t[r][c] = bev[(size_t)(r0 + r) * COUT + c];
    }
    __syncthreads();
    int rl  = threadIdx.x & 63;
    int cc0 = threadIdx.x >> 6;
    #pragma unroll
    for (int i = 0; i < 16; ++i) {
        int ch = cc0 + i * 4;
        out[(size_t)ch * NVOX + r0 + rl] = t[rl][ch];
    }
}

// --------------------------------------------------------------------- launch
extern "C" void kernel_launch(void* const* d_in, const int* in_sizes, int n_in,
                              void* d_out, int out_size, void* d_ws, size_t ws_size,
                              hipStream_t stream) {
    const float* img   = (const float*)d_in[0];
    const float* dw    = (const float*)d_in[1];
    const float* db    = (const float*)d_in[2];
    const float* rots  = (const float*)d_in[3];
    const float* trans = (const float*)d_in[4];
    const float* intr  = (const float*)d_in[5];
    const float* prot  = (const float*)d_in[6];
    const float* ptrn  = (const float*)d_in[7];
    float* out = (float*)d_out;

    char* ws = (char*)d_ws;
    double* cams = (double*)ws;                                   // 4608 B
    float*  feat = (float*)(ws + 8192);                           // 2*24*704*105*4 B
    float*  bev  = (float*)(ws + 8192 + (size_t)2 * NCAM * NPIX * NFEAT * 4); // 4 MB

    hipMemsetAsync(bev, 0, (size_t)NVOX * COUT * sizeof(float), stream);
    setup_cams_k<<<1, 64, 0, stream>>>(rots, trans, intr, prot, ptrn, cams);
    gemm_feat_k<<<528, 512, 0, stream>>>(img, dw, db, feat);
    scatter_k<<<NCAM * NPIX, 64, 0, stream>>>(feat, cams, bev);
    transpose_k<<<NVOX / 64, 256, 0, stream>>>(bev, out);
}